// Round 4
// baseline (170.825 us; speedup 1.0000x reference)
//
#include <hip/hip_runtime.h>
#include <hip/hip_bf16.h>

// Problem constants (match reference)
#define BB      16
#define LL      128
#define LOCM    1024
#define EMBD    16
// SU=100, SL=0, TU=24, TL=0

// out[b,l,j,e] = C1[b,l,e] + mat2[traj_loc[b,l]-1, j] * C2[b,l,e]
//   C1[e] = esl[m][e] + etl[m][e] + dt * (etu[m][e]-etl[m][e]) / 24
//   C2[e] = valid ? (esu[m][e]-esl[m][e]) / 100 : 0
// valid = l < traj_len[b]; m = valid?1:0; dt = vec[b,l] (NOT masked in ref).
//
// MEASUREMENT ROUND: launch the identical kernel TWICE (idempotent writes,
// graph-capture safe). dur = harness_overhead + 2*K; R1 gave overhead + K
// = 149.5 us, so this round's delta measures the kernel's own duration K,
// which rocprof top-5 hides (all five rows are 512 MiB poison fills).

typedef float nfloat4 __attribute__((ext_vector_type(4)));

__global__ __launch_bounds__(256) void embed_kernel(
    const int*   __restrict__ traj_loc,
    const float* __restrict__ mat2,
    const float* __restrict__ vec,
    const int*   __restrict__ traj_len,
    const float* __restrict__ emb_su,
    const float* __restrict__ emb_sl,
    const float* __restrict__ emb_tu,
    const float* __restrict__ emb_tl,
    float*       __restrict__ out)
{
    __shared__ float row[LOCM];

    const int bl = blockIdx.x;          // 0 .. B*L-1
    const int b  = bl >> 7;             // bl / L
    const int l  = bl & (LL - 1);
    const int t  = threadIdx.x;

    const bool valid = l < traj_len[b];
    const int  m     = valid ? 1 : 0;
    const int  loc   = traj_loc[bl] - 1;          // [0, LOCM)
    const float dt   = vec[bl];

    // Stage mat2 row into LDS: 256 threads x 16B = 1024 floats, coalesced.
    const nfloat4* src = (const nfloat4*)(mat2 + (size_t)loc * LOCM);
    ((nfloat4*)row)[t] = src[t];

    // Per-thread C1/C2 over 4 consecutive emb elements; e4 lane fixed = t&3.
    const int e0 = (t & 3) * 4;
    const float inv_t = 1.0f / 24.0f;
    const float inv_s = valid ? (1.0f / 100.0f) : 0.0f;

    float c1[4], c2[4];
    {
        const float* psl = emb_sl + m * EMBD + e0;
        const float* psu = emb_su + m * EMBD + e0;
        const float* ptl = emb_tl + m * EMBD + e0;
        const float* ptu = emb_tu + m * EMBD + e0;
#pragma unroll
        for (int k = 0; k < 4; ++k) {
            const float a_sl = psl[k];
            const float a_su = psu[k];
            const float a_tl = ptl[k];
            const float a_tu = ptu[k];
            c1[k] = a_sl + a_tl + dt * (a_tu - a_tl) * inv_t;
            c2[k] = (a_su - a_sl) * inv_s;
        }
    }

    __syncthreads();

    // Each thread: 16 x 16B stores at flat-f4 index t + 256*i (coalesced:
    // 1 KiB contiguous per wave-instr). LDS read = 4-lane broadcast, 16
    // banks, conflict-free (0 SQ_LDS_BANK_CONFLICT measured).
    nfloat4* dst = ((nfloat4*)(out + (size_t)bl * (LOCM * EMBD))) + t;
    const float* rp = row + (t >> 2);
#pragma unroll
    for (int i = 0; i < 16; ++i) {
        const float ds = rp[64 * i];
        nfloat4 v;
        v.x = fmaf(ds, c2[0], c1[0]);
        v.y = fmaf(ds, c2[1], c1[1]);
        v.z = fmaf(ds, c2[2], c1[2]);
        v.w = fmaf(ds, c2[3], c1[3]);
        dst[256 * i] = v;
    }
}

extern "C" void kernel_launch(void* const* d_in, const int* in_sizes, int n_in,
                              void* d_out, int out_size, void* d_ws, size_t ws_size,
                              hipStream_t stream)
{
    const int*   traj_loc = (const int*)  d_in[0];
    const float* mat2     = (const float*)d_in[1];
    const float* vec      = (const float*)d_in[2];
    const int*   traj_len = (const int*)  d_in[3];
    const float* emb_su_w = (const float*)d_in[4];
    const float* emb_sl_w = (const float*)d_in[5];
    const float* emb_tu_w = (const float*)d_in[6];
    const float* emb_tl_w = (const float*)d_in[7];
    float* out = (float*)d_out;

    dim3 grid(BB * LL);   // 2048 blocks, one per (b,l)
    dim3 block(256);
    // Launch TWICE: second dispatch writes identical values. The delta vs
    // the single-launch round measures the kernel's own duration K.
    embed_kernel<<<grid, block, 0, stream>>>(
        traj_loc, mat2, vec, traj_len,
        emb_su_w, emb_sl_w, emb_tu_w, emb_tl_w, out);
    embed_kernel<<<grid, block, 0, stream>>>(
        traj_loc, mat2, vec, traj_len,
        emb_su_w, emb_sl_w, emb_tu_w, emb_tl_w, out);
}

// Round 5
// 149.186 us; speedup vs baseline: 1.1450x; 1.1450x over previous
//
#include <hip/hip_runtime.h>
#include <hip/hip_bf16.h>

// Problem constants (match reference)
#define BB      16
#define LL      128
#define LOCM    1024
#define EMBD    16
// SU=100, SL=0, TU=24, TL=0

// out[b,l,j,e] = C1[b,l,e] + mat2[traj_loc[b,l]-1, j] * C2[b,l,e]
//   C1[e] = esl[m][e] + etl[m][e] + dt * (etu[m][e]-etl[m][e]) / 24
//   C2[e] = valid ? (esu[m][e]-esl[m][e]) / 100 : 0
// valid = l < traj_len[b]; m = valid?1:0; dt = vec[b,l] (NOT masked in ref).
//
// FINAL: write-BW-roofline kernel. Measured via double-launch delta (R4):
// kernel's own duration K = 21.3 us for 134 MB traffic = 6.3 TB/s, the
// achievable HBM ceiling. Bench dur_us ~149 is dominated by ~128 us of
// harness poison/restore fills (512 MiB ws + 128 MiB out per replay).
// NT stores measured neutral (R3); SQ_LDS_BANK_CONFLICT = 0.

typedef float nfloat4 __attribute__((ext_vector_type(4)));

__global__ __launch_bounds__(256) void embed_kernel(
    const int*   __restrict__ traj_loc,
    const float* __restrict__ mat2,
    const float* __restrict__ vec,
    const int*   __restrict__ traj_len,
    const float* __restrict__ emb_su,
    const float* __restrict__ emb_sl,
    const float* __restrict__ emb_tu,
    const float* __restrict__ emb_tl,
    float*       __restrict__ out)
{
    __shared__ float row[LOCM];

    const int bl = blockIdx.x;          // 0 .. B*L-1
    const int b  = bl >> 7;             // bl / L
    const int l  = bl & (LL - 1);
    const int t  = threadIdx.x;

    const bool valid = l < traj_len[b];
    const int  m     = valid ? 1 : 0;
    const int  loc   = traj_loc[bl] - 1;          // [0, LOCM)
    const float dt   = vec[bl];

    // Stage mat2 row into LDS: 256 threads x 16B = 1024 floats, coalesced.
    const nfloat4* src = (const nfloat4*)(mat2 + (size_t)loc * LOCM);
    ((nfloat4*)row)[t] = src[t];

    // Per-thread C1/C2 over 4 consecutive emb elements; e4 lane fixed = t&3.
    const int e0 = (t & 3) * 4;
    const float inv_t = 1.0f / 24.0f;
    const float inv_s = valid ? (1.0f / 100.0f) : 0.0f;

    float c1[4], c2[4];
    {
        const float* psl = emb_sl + m * EMBD + e0;
        const float* psu = emb_su + m * EMBD + e0;
        const float* ptl = emb_tl + m * EMBD + e0;
        const float* ptu = emb_tu + m * EMBD + e0;
#pragma unroll
        for (int k = 0; k < 4; ++k) {
            const float a_sl = psl[k];
            const float a_su = psu[k];
            const float a_tl = ptl[k];
            const float a_tu = ptu[k];
            c1[k] = a_sl + a_tl + dt * (a_tu - a_tl) * inv_t;
            c2[k] = (a_su - a_sl) * inv_s;
        }
    }

    __syncthreads();

    // Each thread: 16 x 16B stores at flat-f4 index t + 256*i (coalesced:
    // 1 KiB contiguous per wave-instr). LDS read = 4-lane broadcast, 16
    // banks, conflict-free (0 SQ_LDS_BANK_CONFLICT measured).
    nfloat4* dst = ((nfloat4*)(out + (size_t)bl * (LOCM * EMBD))) + t;
    const float* rp = row + (t >> 2);
#pragma unroll
    for (int i = 0; i < 16; ++i) {
        const float ds = rp[64 * i];
        nfloat4 v;
        v.x = fmaf(ds, c2[0], c1[0]);
        v.y = fmaf(ds, c2[1], c1[1]);
        v.z = fmaf(ds, c2[2], c1[2]);
        v.w = fmaf(ds, c2[3], c1[3]);
        dst[256 * i] = v;
    }
}

extern "C" void kernel_launch(void* const* d_in, const int* in_sizes, int n_in,
                              void* d_out, int out_size, void* d_ws, size_t ws_size,
                              hipStream_t stream)
{
    const int*   traj_loc = (const int*)  d_in[0];
    const float* mat2     = (const float*)d_in[1];
    const float* vec      = (const float*)d_in[2];
    const int*   traj_len = (const int*)  d_in[3];
    const float* emb_su_w = (const float*)d_in[4];
    const float* emb_sl_w = (const float*)d_in[5];
    const float* emb_tu_w = (const float*)d_in[6];
    const float* emb_tl_w = (const float*)d_in[7];
    float* out = (float*)d_out;

    dim3 grid(BB * LL);   // 2048 blocks, one per (b,l) — exactly fills 256 CUs x 8 blocks
    dim3 block(256);
    embed_kernel<<<grid, block, 0, stream>>>(
        traj_loc, mat2, vec, traj_len,
        emb_su_w, emb_sl_w, emb_tu_w, emb_tl_w, out);
}